// Round 10
// baseline (346.171 us; speedup 1.0000x reference)
//
#include <hip/hip_runtime.h>

#define CRF_B 256
#define CRF_L 1024
#define CRF_T 128
#define BPB   8                 // batches per block (MFMA rows 0-7)
#define WS_STRIDE 264           // per batch: xf[128], xb[128], kf, kb, gold, pad

typedef __attribute__((ext_vector_type(8))) short bf16x8;
typedef __attribute__((ext_vector_type(4))) float f32x4;

#define MF(a, b, c_) __builtin_amdgcn_mfma_f32_16x16x32_bf16((a), (b), (c_), 0, 0, 0)
// LDS-visibility barrier WITHOUT vmcnt drain (global prefetches stay in flight)
#define WG_BARRIER() asm volatile("s_waitcnt lgkmcnt(0)\n\ts_barrier" ::: "memory")

static __device__ __forceinline__ unsigned short f2bf(float x) {
    union { float f; unsigned u; } v; v.f = x;
    unsigned r = v.u + 0x7FFFu + ((v.u >> 16) & 1u);   // RNE (one-time E build only)
    return (unsigned short)(r >> 16);
}

// all-reduce max over each 16-lane row (VALU-only: DPP, no LDS traffic)
static __device__ __forceinline__ float rowmax16(float v) {
    int x;
    x = __builtin_amdgcn_update_dpp(0, __builtin_bit_cast(int, v), 0xB1,  0xF, 0xF, true); // quad_perm 1,0,3,2
    v = fmaxf(v, __builtin_bit_cast(float, x));
    x = __builtin_amdgcn_update_dpp(0, __builtin_bit_cast(int, v), 0x4E,  0xF, 0xF, true); // quad_perm 2,3,0,1
    v = fmaxf(v, __builtin_bit_cast(float, x));
    x = __builtin_amdgcn_update_dpp(0, __builtin_bit_cast(int, v), 0x141, 0xF, 0xF, true); // row_half_mirror
    v = fmaxf(v, __builtin_bit_cast(float, x));
    x = __builtin_amdgcn_update_dpp(0, __builtin_bit_cast(int, v), 0x140, 0xF, 0xF, true); // row_mirror
    v = fmaxf(v, __builtin_bit_cast(float, x));
    return v;
}

// One recurrence step for 8 batches at once.
// State X [8 batches][128 tags] bf16 in LDS (parity dbuf), XOR-swizzled rows.
// fwd: publish x,   x' = F * (X.E)[*sig]
// bwd: publish F*x, x' = (V.E^T)[*sig]
// Norm: stale per-batch (exact under x*e^kap invariant); partials via DPP +
// s_pm parity buffer, applied on odd steps.
#define STEP(S, PF, DONORM) do {                                               \
    const int  sl_ = (S) & 1;                                                  \
    char* xb_ = s_xraw + sl_ * 4096;                                           \
    float F0_[4], F1_[4];                                                      \
    _Pragma("unroll")                                                          \
    for (int r_ = 0; r_ < 4; ++r_) {                                           \
        F0_[r_] = __expf(PF[r_].x);                                            \
        F1_[r_] = __expf(PF[r_].y);                                            \
    }                                                                          \
    if (g2 < 2) {                                                              \
        _Pragma("unroll")                                                      \
        for (int r_ = 0; r_ < 4; ++r_) {                                       \
            const int row_ = 4 * g2 + r_;                                      \
            float p0_ = isf ? x0[r_] : F0_[r_] * x0[r_];                       \
            float p1_ = isf ? x1[r_] : F1_[r_] * x1[r_];                       \
            unsigned pk_ = (__builtin_bit_cast(unsigned, p1_) & 0xFFFF0000u)   \
                         | (__builtin_bit_cast(unsigned, p0_) >> 16);          \
            *(unsigned*)(xb_ + row_ * 256 + ((tg0 * 2) ^ (row_ << 4))) = pk_;  \
        }                                                                      \
    }                                                                          \
    _Pragma("unroll")                                                          \
    for (int r_ = 0; r_ < 4; ++r_) {                                           \
        int la_ = isf ? (off[r_] + 4 * 512) : (off[r_] - 4 * 512);             \
        if (!isf) la_ = (la_ < base0[r_]) ? base0[r_] : la_;                   \
        PF[r_] = *(const float2*)(fbc + la_);                                  \
        off[r_] += isf ? 512 : -512;                                           \
    }                                                                          \
    WG_BARRIER();                                                              \
    const char* xr_ = xb_ + c * 256;                                           \
    bf16x8 A0_ = *(const bf16x8*)(xr_ + ((  0 + 16 * g2) ^ ((c & 7) << 4)));   \
    bf16x8 A1_ = *(const bf16x8*)(xr_ + (( 64 + 16 * g2) ^ ((c & 7) << 4)));   \
    bf16x8 A2_ = *(const bf16x8*)(xr_ + ((128 + 16 * g2) ^ ((c & 7) << 4)));   \
    bf16x8 A3_ = *(const bf16x8*)(xr_ + ((192 + 16 * g2) ^ ((c & 7) << 4)));   \
    f32x4 dA0_ = MF(A0_, Bf[0][0], Z);  f32x4 dB0_ = MF(A1_, Bf[0][1], Z);     \
    f32x4 dA1_ = MF(A0_, Bf[1][0], Z);  f32x4 dB1_ = MF(A1_, Bf[1][1], Z);     \
    dA0_ = MF(A2_, Bf[0][2], dA0_);  dB0_ = MF(A3_, Bf[0][3], dB0_);           \
    dA1_ = MF(A2_, Bf[1][2], dA1_);  dB1_ = MF(A3_, Bf[1][3], dB1_);           \
    if (DONORM) {                                                              \
        const int pp_ = ((S) >> 1) & 1;                                        \
        const float* pm_ = s_pm + (pp_ ^ 1) * 32 + (g2 & 1) * 4;               \
        f32x4 n0_ = *(const f32x4*)(pm_ + 0);                                  \
        f32x4 n1_ = *(const f32x4*)(pm_ + 8);                                  \
        f32x4 n2_ = *(const f32x4*)(pm_ + 16);                                 \
        f32x4 n3_ = *(const f32x4*)(pm_ + 24);                                 \
        _Pragma("unroll")                                                      \
        for (int r_ = 0; r_ < 4; ++r_) {                                       \
            float nr_ = fmaxf(fmaxf(n0_[r_], n1_[r_]), fmaxf(n2_[r_], n3_[r_]));\
            float sg_ = __builtin_amdgcn_rcpf(nr_);                            \
            kap[r_] += __logf(nr_);                                            \
            float d0_ = (dA0_[r_] + dB0_[r_]) * sg_;                           \
            float d1_ = (dA1_[r_] + dB1_[r_]) * sg_;                           \
            x0[r_] = isf ? F0_[r_] * d0_ : d0_;                                \
            x1[r_] = isf ? F1_[r_] * d1_ : d1_;                                \
        }                                                                      \
    } else {                                                                   \
        _Pragma("unroll")                                                      \
        for (int r_ = 0; r_ < 4; ++r_) {                                       \
            float d0_ = dA0_[r_] + dB0_[r_];                                   \
            float d1_ = dA1_[r_] + dB1_[r_];                                   \
            x0[r_] = isf ? F0_[r_] * d0_ : d0_;                                \
            x1[r_] = isf ? F1_[r_] * d1_ : d1_;                                \
        }                                                                      \
    }                                                                          \
    _Pragma("unroll")                                                          \
    for (int r_ = 0; r_ < 4; ++r_) {                                           \
        bool hit_ = ((S) == msv[r_]);                                          \
        sv0[r_] = hit_ ? x0[r_] : sv0[r_];                                     \
        sv1[r_] = hit_ ? x1[r_] : sv1[r_];                                     \
        svk[r_] = hit_ ? kap[r_] : svk[r_];                                    \
    }                                                                          \
    if (DONORM) {                                                              \
        const int pp_ = ((S) >> 1) & 1;                                        \
        float pmx_[4];                                                         \
        _Pragma("unroll")                                                      \
        for (int r_ = 0; r_ < 4; ++r_)                                         \
            pmx_[r_] = rowmax16(fmaxf(x0[r_], x1[r_]));                        \
        if (c == 0 && g2 < 2) {                                                \
            f32x4 pv_; pv_[0]=pmx_[0]; pv_[1]=pmx_[1]; pv_[2]=pmx_[2]; pv_[3]=pmx_[3]; \
            *(f32x4*)(s_pm + pp_ * 32 + w * 8 + g2 * 4) = pv_;                 \
        }                                                                      \
    }                                                                          \
} while (0)

// 64 blocks x 256 threads: block = (group of 8 batches) x direction.
__global__ __launch_bounds__(256, 1) void forward_kernel(
    const float* __restrict__ trans, const float* __restrict__ feats,
    const int* __restrict__ mask, const int* __restrict__ tags,
    float* __restrict__ ws)
{
    const int bg   = blockIdx.x >> 1;       // batch group (8 batches)
    const int dir  = blockIdx.x & 1;
    const bool isf = (dir == 0);
    const int t    = threadIdx.x;
    const int w    = t >> 6;
    const int lane = t & 63;
    const int g2   = lane >> 4;
    const int c    = lane & 15;
    const int tg0  = 32 * w + 2 * c;        // even tag in [0,128); tg1 = tg0+1

    __shared__ __align__(16) char  s_xraw[2 * 4096];   // X [2][16 rows][128] bf16, swizzled
    __shared__ __align__(16) float s_pm[64];           // [pp][w][g2<2][reg]
    __shared__ int   s_len8[BPB];
    __shared__ float s_gold8[BPB];

    // ---- per-batch length + gold (32 threads per batch) ----
    {
        const int q  = t >> 5;
        const int i0 = t & 31;
        int cnt = 0; float gsum = 0.0f;
        const int base = (bg * BPB + q) * CRF_L;
        for (int l = i0; l < CRF_L; l += 32) {
            if (mask[base + l] != 0) {
                cnt++;
                if (isf) {
                    int tg = tags[base + l];
                    float gv = feats[(size_t)(base + l) * CRF_T + tg];
                    if (l > 0) gv += trans[tags[base + l - 1] * CRF_T + tg];
                    gsum += gv;
                }
            }
        }
        for (int o = 16; o > 0; o >>= 1) {
            cnt  += __shfl_xor(cnt, o, 64);
            gsum += __shfl_xor(gsum, o, 64);
        }
        if (i0 == 0) { s_len8[q] = cnt; s_gold8[q] = gsum; }
    }

    // ---- zero rows 8-15 of both X buffers; init s_pm = 1.0 ----
    {
        unsigned* zp = (unsigned*)s_xraw;
        for (int i = t; i < 2048; i += 256) {
            int buf = i >> 10, word = i & 1023;   // words 0..1023 per buf
            if (word >= 512) zp[buf * 1024 + word] = 0u;   // rows 8-15
        }
        if (t < 64) s_pm[t] = 1.0f;
    }

    // ---- B fragments: fwd E[k][col], bwd E[col][k] ----
    bf16x8 Bf[2][4];
#pragma unroll
    for (int t2 = 0; t2 < 2; ++t2) {
        const int col = tg0 + t2;
#pragma unroll
        for (int kt = 0; kt < 4; ++kt)
#pragma unroll
            for (int e = 0; e < 8; ++e) {
                int k = 32 * kt + 8 * g2 + e;
                int idx = isf ? (k * CRF_T + col) : (col * CRF_T + k);
                Bf[t2][kt][e] = (short)f2bf(__expf(trans[idx]));
            }
    }

    __syncthreads();

    int nsteps = 0;
#pragma unroll
    for (int qq = 0; qq < BPB; ++qq) {
        int L_ = s_len8[qq];
        int ns_ = isf ? (L_ >> 1) : ((L_ - 1) >> 1);
        nsteps = (ns_ > nsteps) ? ns_ : nsteps;
    }

    const char* fbc = (const char*)feats;
    int msv[4], off[4], base0[4];
    float x0[4], x1[4], kap[4], sv0[4], sv1[4], svk[4];
    float2 pfA[4], pfB[4], pfC[4], pfD[4];

#pragma unroll
    for (int r = 0; r < 4; ++r) {
        const int qi = 4 * (g2 & 1) + r;                    // 0..7 (dup for g2>=2)
        const int qb = bg * BPB + qi;
        const int len = s_len8[qi];
        msv[r]   = isf ? (len >> 1) : ((len - 1) >> 1);
        base0[r] = qb * (CRF_L * CRF_T * 4) + tg0 * 4;
        kap[r] = 0.0f;
        if (isf) {
            float2 v0 = *(const float2*)(fbc + base0[r]);           // row 0
            x0[r] = __expf(v0.x); x1[r] = __expf(v0.y);
            off[r] = base0[r] + 512;                                 // row 1
            pfA[r] = *(const float2*)(fbc + off[r]);
            pfB[r] = *(const float2*)(fbc + off[r] + 512);
            pfC[r] = *(const float2*)(fbc + off[r] + 1024);
            pfD[r] = *(const float2*)(fbc + off[r] + 1536);
        } else {
            x0[r] = 1.0f; x1[r] = 1.0f;
            off[r] = base0[r] + (len - 1) * 512;                     // row len-1
            pfA[r] = *(const float2*)(fbc + off[r]);
            pfB[r] = *(const float2*)(fbc + off[r] - 512);
            pfC[r] = *(const float2*)(fbc + off[r] - 1024);
            pfD[r] = *(const float2*)(fbc + off[r] - 1536);
        }
        sv0[r] = x0[r]; sv1[r] = x1[r]; svk[r] = 0.0f;
    }

    const f32x4 Z = {};

    const int lim = 1 + (nsteps & ~3);
    int s = 1;
    for (; s < lim; s += 4) {
        STEP(s,     pfA, true);
        STEP(s + 1, pfB, false);
        STEP(s + 2, pfC, true);
        STEP(s + 3, pfD, false);
    }
    if (s <= nsteps) { STEP(s, pfA, true);  s++; }
    if (s <= nsteps) { STEP(s, pfB, false); s++; }
    if (s <= nsteps) { STEP(s, pfC, true); }

    // ---- write saved midpoint states ----
    if (g2 < 2) {
#pragma unroll
        for (int r = 0; r < 4; ++r) {
            const int qb = bg * BPB + 4 * g2 + r;
            float2 vv; vv.x = sv0[r]; vv.y = sv1[r];
            *(float2*)(ws + (size_t)qb * WS_STRIDE + dir * 128 + tg0) = vv;
            if (c == 0 && w == 0) {
                ws[(size_t)qb * WS_STRIDE + 256 + dir] = svk[r];
                if (isf) ws[(size_t)qb * WS_STRIDE + 258] = s_gold8[4 * g2 + r];
            }
        }
    }
}

// one block, thread t = batch t: loss_b = kf + kb + log(sum xf.xb) - gold
__global__ __launch_bounds__(256) void combine_kernel(
    const float* __restrict__ ws, float* __restrict__ out)
{
    const int t    = threadIdx.x;
    const int lane = t & 63;
    const int w    = t >> 6;
    const float4* pf = (const float4*)(ws + (size_t)t * WS_STRIDE);
    const float4* pb = pf + 32;
    float dot = 0.0f;
#pragma unroll
    for (int k = 0; k < 32; ++k) {
        float4 a = pf[k], bb = pb[k];
        dot += a.x * bb.x + a.y * bb.y + a.z * bb.z + a.w * bb.w;
    }
    const float* ps = ws + (size_t)t * WS_STRIDE;
    float val = ps[256] + ps[257] + __logf(dot) - ps[258];
    for (int o = 32; o > 0; o >>= 1) val += __shfl_down(val, o, 64);
    __shared__ float sw[4];
    if (lane == 0) sw[w] = val;
    __syncthreads();
    if (t == 0) out[0] = sw[0] + sw[1] + sw[2] + sw[3];
}

extern "C" void kernel_launch(void* const* d_in, const int* in_sizes, int n_in,
                              void* d_out, int out_size, void* d_ws, size_t ws_size,
                              hipStream_t stream) {
    const float* trans = (const float*)d_in[0];
    const float* feats = (const float*)d_in[1];
    const int*   mask  = (const int*)d_in[2];
    const int*   tags  = (const int*)d_in[3];
    float*       out   = (float*)d_out;
    float*       ws    = (float*)d_ws;

    hipLaunchKernelGGL(forward_kernel, dim3(2 * CRF_B / BPB), dim3(256), 0, stream,
                       trans, feats, mask, tags, ws);
    hipLaunchKernelGGL(combine_kernel, dim3(1), dim3(256), 0, stream, ws, out);
}

// Round 11
// 311.052 us; speedup vs baseline: 1.1129x; 1.1129x over previous
//
#include <hip/hip_runtime.h>

#define CRF_B 256
#define CRF_L 1024
#define CRF_T 128
#define WS_STRIDE 264   // per batch: xf[128], xb[128], kf, kb, gold, pad

typedef __attribute__((ext_vector_type(8))) short bf16x8;
typedef __attribute__((ext_vector_type(4))) float f32x4;
typedef __attribute__((ext_vector_type(2))) short short2v;

#define MF(a, b, c_) __builtin_amdgcn_mfma_f32_16x16x32_bf16((a), (b), (c_), 0, 0, 0)
// LDS-visibility barrier WITHOUT vmcnt drain (global prefetches stay in flight)
#define WG_BARRIER() asm volatile("s_waitcnt lgkmcnt(0)\n\ts_barrier" ::: "memory")

static __device__ __forceinline__ unsigned short f2bf(float x) {
    union { float f; unsigned u; } v; v.f = x;
    unsigned r = v.u + 0x7FFFu + ((v.u >> 16) & 1u);   // RNE (one-time E build)
    return (unsigned short)(r >> 16);
}
// truncating bf16 pair pack [b:a] — 2 ops, on the chain
static __device__ __forceinline__ unsigned pack2(float a, float b) {
    return (__builtin_bit_cast(unsigned, b) & 0xFFFF0000u) |
           (__builtin_bit_cast(unsigned, a) >> 16);
}
static __device__ __forceinline__ short2v bmax2(short2v a, short2v b) {
    return __builtin_elementwise_max(a, b);   // bf16>=0: i16 order-preserving
}
static __device__ __forceinline__ short2v fragmax(bf16x8 a) {
    short2v q0 = __builtin_shufflevector(a, a, 0, 1);
    short2v q1 = __builtin_shufflevector(a, a, 2, 3);
    short2v q2 = __builtin_shufflevector(a, a, 4, 5);
    short2v q3 = __builtin_shufflevector(a, a, 6, 7);
    return bmax2(bmax2(q0, q1), bmax2(q2, q3));
}

// One step. Chain: pack -> ds_write_b64 -> barrier -> 4x ds_read_b128 ->
// 2-deep MFMA -> add -> mul. sig/lognrm are STALE (computed last step,
// off-chain); kap += lognrm exactly when the sig is applied.
// fwd: publish x, x' = (F*sig)*d.  bwd: publish (F*sig)*x, x' = d.
#define STEP(PFv) do {                                                        \
    kap += lognrm;                                                            \
    float Fs0_ = Fcur[0]*sig, Fs1_ = Fcur[1]*sig,                             \
          Fs2_ = Fcur[2]*sig, Fs3_ = Fcur[3]*sig;                             \
    if (g2 == 0) {                                                            \
        unsigned lo_, hi_;                                                    \
        if (isf) { lo_ = pack2(x[0], x[1]); hi_ = pack2(x[2], x[3]); }        \
        else     { lo_ = pack2(Fs0_*x[0], Fs1_*x[1]);                         \
                   hi_ = pack2(Fs2_*x[2], Fs3_*x[3]); }                       \
        *(unsigned long long*)(s_x + sloff + 128*W + 8*c) =                   \
            ((unsigned long long)hi_ << 32) | lo_;                            \
    }                                                                         \
    _Pragma("unroll")                                                         \
    for (int m_ = 0; m_ < 4; ++m_) {                                          \
        Fcur[m_] = __expf(PFv[m_]);                                           \
        PFv[m_]  = *(const float*)(fptr + fcol[m_]);                          \
    }                                                                         \
    fptr += fstep;                                                            \
    WG_BARRIER();                                                             \
    const char* xr_ = s_x + sloff;                                            \
    bf16x8 A0_ = *(const bf16x8*)(xr_ +   0 + 16*g2);                         \
    bf16x8 A1_ = *(const bf16x8*)(xr_ +  64 + 16*g2);                         \
    bf16x8 A2_ = *(const bf16x8*)(xr_ + 128 + 16*g2);                         \
    bf16x8 A3_ = *(const bf16x8*)(xr_ + 192 + 16*g2);                         \
    sloff ^= 256;                                                             \
    f32x4 p0a = MF(A0_, Bf[0][0], Z); f32x4 p0b = MF(A1_, Bf[0][1], Z);       \
    f32x4 p1a = MF(A0_, Bf[1][0], Z); f32x4 p1b = MF(A1_, Bf[1][1], Z);       \
    f32x4 p2a = MF(A0_, Bf[2][0], Z); f32x4 p2b = MF(A1_, Bf[2][1], Z);       \
    f32x4 p3a = MF(A0_, Bf[3][0], Z); f32x4 p3b = MF(A1_, Bf[3][1], Z);       \
    p0a = MF(A2_, Bf[0][2], p0a); p0b = MF(A3_, Bf[0][3], p0b);               \
    p1a = MF(A2_, Bf[1][2], p1a); p1b = MF(A3_, Bf[1][3], p1b);               \
    p2a = MF(A2_, Bf[2][2], p2a); p2b = MF(A3_, Bf[2][3], p2b);               \
    p3a = MF(A2_, Bf[3][2], p3a); p3b = MF(A3_, Bf[3][3], p3b);               \
    float d0_ = p0a[0] + p0b[0], d1_ = p1a[0] + p1b[0];                       \
    float d2_ = p2a[0] + p2b[0], d3_ = p3a[0] + p3b[0];                       \
    if (isf) { x[0] = Fs0_*d0_; x[1] = Fs1_*d1_;                              \
               x[2] = Fs2_*d2_; x[3] = Fs3_*d3_; }                            \
    else     { x[0] = d0_; x[1] = d1_; x[2] = d2_; x[3] = d3_; }              \
    short2v mx_ = bmax2(bmax2(fragmax(A0_), fragmax(A1_)),                    \
                        bmax2(fragmax(A2_), fragmax(A3_)));                   \
    unsigned mu_ = __builtin_bit_cast(unsigned, mx_);                         \
    float nm_ = fmaxf(__builtin_bit_cast(float, mu_ << 16),                   \
                      __builtin_bit_cast(float, mu_ & 0xFFFF0000u));          \
    nm_ = fmaxf(nm_, __shfl_xor(nm_, 16, 64));                                \
    nm_ = fmaxf(nm_, __shfl_xor(nm_, 32, 64));                                \
    sig    = __builtin_amdgcn_rcpf(nm_);                                      \
    lognrm = __logf(nm_);                                                     \
} while (0)

// 512 blocks x 128 threads (2 waves): block = one direction of one batch.
// Wave W owns cols [64W, 64W+64) as 4 col-tiles; lane c owns cols 64W+16m+c.
// x stored PERMUTED in LDS: col j at pos 64*(j>>6) + 4*(j&15) + ((j>>4)&3),
// so each lane's 4 values are one b64. B built with the same sigma (operand
// symmetry => any shared bijection is correct).
__global__ __launch_bounds__(128, 1) void forward_kernel(
    const float* __restrict__ trans, const float* __restrict__ feats,
    const int* __restrict__ mask, const int* __restrict__ tags,
    float* __restrict__ ws)
{
    const int b    = blockIdx.x >> 1;
    const int dir  = blockIdx.x & 1;
    const bool isf = (dir == 0);
    const int t    = threadIdx.x;      // 0..127
    const int W    = t >> 6;
    const int lane = t & 63;
    const int g2   = lane >> 4;
    const int c    = lane & 15;

    __shared__ __align__(16) char s_x[512];   // [2 parity][128] bf16, permuted
    __shared__ int   s_len;
    __shared__ float s_gold;

    if (t == 0) { s_len = 0; s_gold = 0.0f; }
    __syncthreads();

    // ---- per-batch length (+ gold, fwd block only) ----
    {
        int cnt = 0; float gsum = 0.0f;
        const int base = b * CRF_L;
        for (int l = t; l < CRF_L; l += 128) {
            if (mask[base + l] != 0) {
                cnt++;
                if (isf) {
                    int tg = tags[base + l];
                    float gv = feats[(size_t)(base + l) * CRF_T + tg];
                    if (l > 0) gv += trans[tags[base + l - 1] * CRF_T + tg];
                    gsum += gv;
                }
            }
        }
        for (int o = 32; o > 0; o >>= 1) {
            cnt  += __shfl_down(cnt, o, 64);
            gsum += __shfl_down(gsum, o, 64);
        }
        if (lane == 0) { atomicAdd(&s_len, cnt); if (isf) atomicAdd(&s_gold, gsum); }
    }

    // ---- B fragments with permuted k-map sigma(pos) ----
    bf16x8 Bf[4][4];
#pragma unroll
    for (int m = 0; m < 4; ++m) {
        const int col = 64 * W + 16 * m + c;
#pragma unroll
        for (int kt = 0; kt < 4; ++kt)
#pragma unroll
            for (int e = 0; e < 8; ++e) {
                int pos  = 32 * kt + 8 * g2 + e;
                int ktag = 64 * (pos >> 6) + 16 * (pos & 3) + ((pos >> 2) & 15);
                int idx  = isf ? (ktag * CRF_T + col) : (col * CRF_T + ktag);
                Bf[m][kt][e] = (short)f2bf(__expf(trans[idx]));
            }
    }

    __syncthreads();
    const int len    = s_len;                  // in [512, 1024]
    const int mmid   = len >> 1;
    const int nsteps = isf ? mmid : (len - 1 - mmid);

    const char* fb = (const char*)feats + (size_t)b * CRF_L * CRF_T * 4;
    int fcol[4];
#pragma unroll
    for (int m = 0; m < 4; ++m) fcol[m] = (64 * W + 16 * m + c) * 4;
#define ROWP(r) (fb + (size_t)(r) * 512)

    float x[4], Fcur[4], pfA[4], pfB[4], pfC[4], pfD[4];
    float kap = 0.0f, sig = 1.0f, lognrm = 0.0f;

    if (isf) {
#pragma unroll
        for (int m = 0; m < 4; ++m) {
            x[m]    = __expf(*(const float*)(ROWP(0) + fcol[m]));
            Fcur[m] = __expf(*(const float*)(ROWP(1) + fcol[m]));
            pfA[m]  = *(const float*)(ROWP(2) + fcol[m]);
            pfB[m]  = *(const float*)(ROWP(3) + fcol[m]);
            pfC[m]  = *(const float*)(ROWP(4) + fcol[m]);
            pfD[m]  = *(const float*)(ROWP(5) + fcol[m]);
        }
    } else {
#pragma unroll
        for (int m = 0; m < 4; ++m) {
            x[m]    = 1.0f;
            Fcur[m] = __expf(*(const float*)(ROWP(len - 1) + fcol[m]));
            pfA[m]  = *(const float*)(ROWP(len - 2) + fcol[m]);
            pfB[m]  = *(const float*)(ROWP(len - 3) + fcol[m]);
            pfC[m]  = *(const float*)(ROWP(len - 4) + fcol[m]);
            pfD[m]  = *(const float*)(ROWP(len - 5) + fcol[m]);
        }
    }
    const char* fptr = isf ? ROWP(6) : ROWP(len - 6);   // rows S+5 stay in-bounds
    const int   fstep = isf ? 512 : -512;
    unsigned sloff = 0;
    const f32x4 Z = {};

    int s = 0;
    for (; s + 4 <= nsteps; s += 4) { STEP(pfA); STEP(pfB); STEP(pfC); STEP(pfD); }
    if (s < nsteps) { STEP(pfA); s++; }
    if (s < nsteps) { STEP(pfB); s++; }
    if (s < nsteps) { STEP(pfC); }

    // ---- write half-chain state: fwd -> a_mid, bwd -> b_mid ----
    float* wsb = ws + (size_t)b * WS_STRIDE;
    if (g2 == 0) {
#pragma unroll
        for (int m = 0; m < 4; ++m)
            wsb[dir * 128 + 64 * W + 16 * m + c] = x[m];
    }
    if (t == 0) { wsb[256 + dir] = kap; if (isf) wsb[258] = s_gold; }
}

// one block, thread t = batch t: loss_b = kf + kb + log(sum xf.xb) - gold
__global__ __launch_bounds__(256) void combine_kernel(
    const float* __restrict__ ws, float* __restrict__ out)
{
    const int t    = threadIdx.x;
    const int lane = t & 63;
    const int w    = t >> 6;
    const float4* pf = (const float4*)(ws + (size_t)t * WS_STRIDE);
    const float4* pb = pf + 32;
    float dot = 0.0f;
#pragma unroll
    for (int k = 0; k < 32; ++k) {
        float4 a = pf[k], bb = pb[k];
        dot += a.x * bb.x + a.y * bb.y + a.z * bb.z + a.w * bb.w;
    }
    const float* ps = ws + (size_t)t * WS_STRIDE;
    float val = ps[256] + ps[257] + __logf(dot) - ps[258];
    for (int o = 32; o > 0; o >>= 1) val += __shfl_down(val, o, 64);
    __shared__ float sw[4];
    if (lane == 0) sw[w] = val;
    __syncthreads();
    if (t == 0) out[0] = sw[0] + sw[1] + sw[2] + sw[3];
}

extern "C" void kernel_launch(void* const* d_in, const int* in_sizes, int n_in,
                              void* d_out, int out_size, void* d_ws, size_t ws_size,
                              hipStream_t stream) {
    const float* trans = (const float*)d_in[0];
    const float* feats = (const float*)d_in[1];
    const int*   mask  = (const int*)d_in[2];
    const int*   tags  = (const int*)d_in[3];
    float*       out   = (float*)d_out;
    float*       ws    = (float*)d_ws;

    hipLaunchKernelGGL(forward_kernel, dim3(2 * CRF_B), dim3(128), 0, stream,
                       trans, feats, mask, tags, ws);
    hipLaunchKernelGGL(combine_kernel, dim3(1), dim3(256), 0, stream, ws, out);
}